// Round 1
// baseline (2292.223 us; speedup 1.0000x reference)
//
#include <hip/hip_runtime.h>
#include <hip/hip_bf16.h>
#include <cmath>

typedef unsigned short ushort_t;
typedef __attribute__((ext_vector_type(8))) short short8;
typedef __attribute__((ext_vector_type(4))) float float4_t;

// ---- problem constants ----
static constexpr int BB   = 2;
static constexpr int SS   = 2048;
static constexpr int DIM  = 2048;
static constexpr int HH   = 16;
static constexpr int DN   = 128;
static constexpr int DR   = 64;
static constexpr int CKV  = 512;
static constexpr int QKH  = DN + DR;          // 192
static constexpr int NCAT = HH * QKH + CKV + DR;  // 3648
static constexpr int NPAD = 3712;             // 29 * 128
static constexpr int MM   = BB * SS;          // 4096

__device__ __forceinline__ float b2f(ushort_t u) {
  return __uint_as_float(((unsigned)u) << 16);
}
__device__ __forceinline__ ushort_t f2b(float f) {
  unsigned u = __float_as_uint(f);
  u += 0x7FFFu + ((u >> 16) & 1u);
  return (ushort_t)(u >> 16);
}

__device__ __forceinline__ void store_val(ushort_t* p, float v) { *p = f2b(v); }
__device__ __forceinline__ void store_val(float* p, float v)    { *p = v; }

// ---------------- conversion kernels ----------------
__global__ void f32_to_bf16_k(const float* __restrict__ in, ushort_t* __restrict__ out, long n) {
  long i = (long)blockIdx.x * blockDim.x + threadIdx.x;
  long stride = (long)gridDim.x * blockDim.x;
  for (; i < n; i += stride) out[i] = f2b(in[i]);
}

__global__ void build_wcat_k(const float* __restrict__ wq, const float* __restrict__ wkva,
                             ushort_t* __restrict__ wcat) {
  const long n = (long)NPAD * DIM;
  long i = (long)blockIdx.x * blockDim.x + threadIdx.x;
  long stride = (long)gridDim.x * blockDim.x;
  for (; i < n; i += stride) {
    int r = (int)(i >> 11);   // DIM = 2048
    float v;
    if (r < HH * QKH)      v = wq[i];
    else if (r < NCAT)     v = wkva[i - (long)(HH * QKH) * DIM];
    else                   v = 0.f;
    wcat[i] = f2b(v);
  }
}

// wkv_b (4096, 512) -> wbT (h, 512, 128) transposed nope part, wbv (h, 128, 512) v part
__global__ void build_wb_k(const float* __restrict__ wkvb, ushort_t* __restrict__ wbT,
                           ushort_t* __restrict__ wbv) {
  const long n = (long)4096 * 512;
  long i = (long)blockIdx.x * blockDim.x + threadIdx.x;
  long stride = (long)gridDim.x * blockDim.x;
  for (; i < n; i += stride) {
    int c  = (int)(i & 511);
    int rr = (int)(i >> 9);
    int h = rr >> 8, d = rr & 255;
    ushort_t v = f2b(wkvb[i]);
    if (d < DN) wbT[((long)h * CKV + c) * DN + d] = v;
    else        wbv[((long)h * DN + (d - DN)) * CKV + c] = v;
  }
}

// ---------------- GEMM: C(M,N) = A(M,K) @ W(N,K)^T ----------------
// 128x128 tile, BK=32, 4 waves (2x2), each wave 64x64 via 4x4 16x16 fragments.
template <typename OutT>
__global__ __launch_bounds__(256, 2)
void gemm_bt(const ushort_t* __restrict__ A, const ushort_t* __restrict__ Bw,
             OutT* __restrict__ C, int K, int lda, int ldb, int ldc,
             long aZ, long bZ, long cZ) {
  A  += (long)blockIdx.z * aZ;
  Bw += (long)blockIdx.z * bZ;
  C  += (long)blockIdx.z * cZ;
  __shared__ ushort_t As[128 * 32];
  __shared__ ushort_t Bs[128 * 32];
  const int tid = threadIdx.x;
  const int l = tid & 63, w = tid >> 6;
  const int wr = w >> 1, wc = w & 1;
  const int m0 = blockIdx.x * 128, n0 = blockIdx.y * 128;
  const int lr = tid >> 2;            // 0..63
  const int lc = (tid & 3) << 3;      // 0,8,16,24
  const int fr = l & 15;              // fragment row
  const int fk = (l >> 4) << 3;       // fragment k offset

  const float4_t zero = {0.f, 0.f, 0.f, 0.f};
  float4_t acc[4][4];
#pragma unroll
  for (int mi = 0; mi < 4; mi++)
#pragma unroll
    for (int ni = 0; ni < 4; ni++) acc[mi][ni] = zero;

  for (int k0 = 0; k0 < K; k0 += 32) {
    short8 a0 = *(const short8*)(A + (long)(m0 + lr) * lda + k0 + lc);
    short8 a1 = *(const short8*)(A + (long)(m0 + 64 + lr) * lda + k0 + lc);
    short8 b0 = *(const short8*)(Bw + (long)(n0 + lr) * ldb + k0 + lc);
    short8 b1 = *(const short8*)(Bw + (long)(n0 + 64 + lr) * ldb + k0 + lc);
    __syncthreads();
    *(short8*)&As[lr * 32 + lc] = a0;
    *(short8*)&As[(64 + lr) * 32 + lc] = a1;
    *(short8*)&Bs[lr * 32 + lc] = b0;
    *(short8*)&Bs[(64 + lr) * 32 + lc] = b1;
    __syncthreads();
    short8 af[4], bf[4];
#pragma unroll
    for (int i = 0; i < 4; i++) af[i] = *(const short8*)&As[(wr * 64 + i * 16 + fr) * 32 + fk];
#pragma unroll
    for (int i = 0; i < 4; i++) bf[i] = *(const short8*)&Bs[(wc * 64 + i * 16 + fr) * 32 + fk];
#pragma unroll
    for (int mi = 0; mi < 4; mi++)
#pragma unroll
      for (int ni = 0; ni < 4; ni++)
        acc[mi][ni] = __builtin_amdgcn_mfma_f32_16x16x32_bf16(af[mi], bf[ni], acc[mi][ni], 0, 0, 0);
  }

  const int rr = (l >> 4) << 2;
#pragma unroll
  for (int mi = 0; mi < 4; mi++)
#pragma unroll
    for (int ni = 0; ni < 4; ni++)
#pragma unroll
      for (int r = 0; r < 4; r++) {
        int row = m0 + wr * 64 + mi * 16 + rr + r;
        int col = n0 + wc * 64 + ni * 16 + fr;
        store_val(&C[(long)row * ldc + col], acc[mi][ni][r]);
      }
}

// ---------------- postproc: RoPE + RMSNorm + reorders ----------------
// Y: (4096, 3712) bf16.  Writes qnope (h,4096,128), qpe (h,4096,64), Kext (4096, 576)
__global__ __launch_bounds__(256)
void postproc_k(const ushort_t* __restrict__ Y, const float* __restrict__ fcos,
                const float* __restrict__ fsin, const float* __restrict__ kvw,
                ushort_t* __restrict__ qnope, ushort_t* __restrict__ qpe,
                ushort_t* __restrict__ Kext) {
  const int m = blockIdx.x;        // 0..4095  (b*2048 + s)
  const int s = m & (SS - 1);
  const int t = threadIdx.x;       // 0..255
  const ushort_t* Yr = Y + (long)m * NPAD;

  // rmsnorm over cols [3072, 3584)
  float v0 = b2f(Yr[3072 + t]);
  float v1 = b2f(Yr[3328 + t]);
  float ss = v0 * v0 + v1 * v1;
#pragma unroll
  for (int off = 32; off >= 1; off >>= 1) ss += __shfl_xor(ss, off, 64);
  __shared__ float red[4];
  if ((t & 63) == 0) red[t >> 6] = ss;
  __syncthreads();
  float tot = red[0] + red[1] + red[2] + red[3];
  float rinv = rsqrtf(tot * (1.f / 512.f) + 1e-6f);

  ushort_t* Kr = Kext + (long)m * 576;
  Kr[t]       = f2b(v0 * rinv * kvw[t]);
  Kr[256 + t] = f2b(v1 * rinv * kvw[256 + t]);

  if (t < 32) {  // k_pe rope
    float x0 = b2f(Yr[3584 + 2 * t]);
    float x1 = b2f(Yr[3585 + 2 * t]);
    float c = fcos[s * 32 + t], sn = fsin[s * 32 + t];
    Kr[512 + 2 * t]     = f2b(x0 * c - x1 * sn);
    Kr[512 + 2 * t + 1] = f2b(x0 * sn + x1 * c);
  }

  // qnope reorder: (m, h*192 + d) -> (h, m, d)
#pragma unroll
  for (int i = 0; i < 8; i++) {
    int idx = t + i * 256;       // 0..2047
    int h = idx >> 7, d = idx & 127;
    qnope[((long)h * MM + m) * DN + d] = Yr[h * QKH + d];
  }
  // q_pe rope: (m, h*192 + 128 + 2j) -> (h, m, 2j)
#pragma unroll
  for (int i = 0; i < 2; i++) {
    int p = t + i * 256;         // 0..511
    int h = p >> 5, j = p & 31;
    float x0 = b2f(Yr[h * QKH + DN + 2 * j]);
    float x1 = b2f(Yr[h * QKH + DN + 2 * j + 1]);
    float c = fcos[s * 32 + j], sn = fsin[s * 32 + j];
    qpe[((long)h * MM + m) * DR + 2 * j]     = f2b(x0 * c - x1 * sn);
    qpe[((long)h * MM + m) * DR + 2 * j + 1] = f2b(x0 * sn + x1 * c);
  }
}

// ---------------- flash attention (MLA, shared latent KV) ----------------
// grid (S/64, B*H), block 256 (4 waves); wave w owns q rows [qb*64 + 16w, +16).
// QK over 576 dims (K-frags from global, L2 resident), V = kv_n (512) via LDS transpose.
__global__ __launch_bounds__(256, 1)
void attn_k(const ushort_t* __restrict__ qabs, const ushort_t* __restrict__ qpe,
            const ushort_t* __restrict__ Kext, ushort_t* __restrict__ O, float scale) {
  __shared__ ushort_t Vt[512 * 40];       // V^T tile: Vt[c][t], pitch 40
  __shared__ ushort_t Pl[4][16 * 40];     // per-wave P tile, pitch 40

  const int qb = blockIdx.x;
  const int bh = blockIdx.y;
  const int b = bh >> 4, h = bh & 15;
  const int tid = threadIdx.x, w = tid >> 6, l = tid & 63;
  const int fr = l & 15;        // fragment row/col index
  const int kg = l >> 4;        // k-group
  const int qbase = qb * 64;
  const long kvbase = (long)b * SS;
  const int wq0 = qbase + w * 16;

  // Q fragments (rows = fr)
  const long qrow = kvbase + wq0 + fr;
  const ushort_t* qa = qabs + ((long)h * MM + qrow) * CKV;
  const ushort_t* qp = qpe + ((long)h * MM + qrow) * DR;
  short8 af[18];
#pragma unroll
  for (int kk = 0; kk < 16; kk++) af[kk] = *(const short8*)(qa + kk * 32 + kg * 8);
  af[16] = *(const short8*)(qp + kg * 8);
  af[17] = *(const short8*)(qp + 32 + kg * 8);

  const float4_t zero = {0.f, 0.f, 0.f, 0.f};
  float4_t oacc[32];
#pragma unroll
  for (int nc = 0; nc < 32; nc++) oacc[nc] = zero;
  float mrow[4] = {-1e30f, -1e30f, -1e30f, -1e30f};
  float lrow[4] = {0.f, 0.f, 0.f, 0.f};

  for (int t0 = 0; t0 < qbase + 64; t0 += 32) {
    // stage V^T (first 512 cols of Kext rows t0..t0+31), r fast over lanes for bank spread
#pragma unroll
    for (int cc = 0; cc < 8; cc++) {
      int ch = tid + cc * 256;
      int r = ch & 31;
      int c8 = (ch >> 5) << 3;    // 0..504
      short8 v = *(const short8*)(Kext + (kvbase + t0 + r) * 576 + c8);
#pragma unroll
      for (int j = 0; j < 8; j++) Vt[(c8 + j) * 40 + r] = (ushort_t)v[j];
    }
    __syncthreads();

    // QK^T: D[q][t],  q = kg*4 + r, t = nf*16 + fr
    float4_t sc[2] = {zero, zero};
    const ushort_t* kb = Kext + (kvbase + t0) * 576;
#pragma unroll
    for (int nf = 0; nf < 2; nf++) {
      const ushort_t* kr = kb + (long)(nf * 16 + fr) * 576 + kg * 8;
#pragma unroll
      for (int kk = 0; kk < 18; kk++) {
        short8 bfr = *(const short8*)(kr + kk * 32);
        sc[nf] = __builtin_amdgcn_mfma_f32_16x16x32_bf16(af[kk], bfr, sc[nf], 0, 0, 0);
      }
    }

    // scale + causal mask
    float pm[2][4];
#pragma unroll
    for (int nf = 0; nf < 2; nf++)
#pragma unroll
      for (int r = 0; r < 4; r++) {
        float v = sc[nf][r] * scale;
        int tg = t0 + nf * 16 + fr;
        int qg = wq0 + kg * 4 + r;
        pm[nf][r] = (tg <= qg) ? v : -1e30f;
      }

    // online softmax (reduce across fr lanes)
    float alpha[4];
#pragma unroll
    for (int r = 0; r < 4; r++) {
      float tm = fmaxf(pm[0][r], pm[1][r]);
#pragma unroll
      for (int off = 1; off <= 8; off <<= 1) tm = fmaxf(tm, __shfl_xor(tm, off, 64));
      float mnew = fmaxf(mrow[r], tm);
      alpha[r] = __expf(mrow[r] - mnew);
      float p0 = __expf(pm[0][r] - mnew);
      float p1 = __expf(pm[1][r] - mnew);
      Pl[w][(kg * 4 + r) * 40 + fr]      = f2b(p0);
      Pl[w][(kg * 4 + r) * 40 + 16 + fr] = f2b(p1);
      float ts = p0 + p1;
#pragma unroll
      for (int off = 1; off <= 8; off <<= 1) ts += __shfl_xor(ts, off, 64);
      lrow[r] = alpha[r] * lrow[r] + ts;
      mrow[r] = mnew;
    }

    // rescale O
#pragma unroll
    for (int nc = 0; nc < 32; nc++)
#pragma unroll
      for (int r = 0; r < 4; r++) oacc[nc][r] *= alpha[r];

    // PV: A = P (16q x 32t), B = V (t x c) from Vt
    short8 pa = *(const short8*)&Pl[w][fr * 40 + kg * 8];
#pragma unroll
    for (int nc = 0; nc < 32; nc++) {
      short8 bv = *(const short8*)&Vt[(nc * 16 + fr) * 40 + kg * 8];
      oacc[nc] = __builtin_amdgcn_mfma_f32_16x16x32_bf16(pa, bv, oacc[nc], 0, 0, 0);
    }
    __syncthreads();
  }

  // epilogue
  float invl[4];
#pragma unroll
  for (int r = 0; r < 4; r++) invl[r] = 1.f / lrow[r];
  ushort_t* orow = O + ((long)h * MM + kvbase + wq0) * CKV;
#pragma unroll
  for (int nc = 0; nc < 32; nc++)
#pragma unroll
    for (int r = 0; r < 4; r++)
      orow[(long)(kg * 4 + r) * CKV + nc * 16 + fr] = f2b(oacc[nc][r] * invl[r]);
}

// ---------------- launch ----------------
extern "C" void kernel_launch(void* const* d_in, const int* in_sizes, int n_in,
                              void* d_out, int out_size, void* d_ws, size_t ws_size,
                              hipStream_t stream) {
  const float* x    = (const float*)d_in[0];
  const float* fcos = (const float*)d_in[2];
  const float* fsin = (const float*)d_in[3];
  const float* wq   = (const float*)d_in[4];
  const float* wkva = (const float*)d_in[5];
  const float* kvw  = (const float*)d_in[6];
  const float* wkvb = (const float*)d_in[7];
  const float* wo   = (const float*)d_in[8];
  float* out = (float*)d_out;
  char* ws = (char*)d_ws;

  // workspace layout (bytes)
  const size_t O_WCAT = 0;
  const size_t O_WBT  = O_WCAT + (size_t)NPAD * DIM * 2;       // wcat  (3712,2048)
  const size_t O_WBV  = O_WBT + (size_t)HH * CKV * DN * 2;     // wbT   (h,512,128)
  const size_t O_WO   = O_WBV + (size_t)HH * DN * CKV * 2;     // wbv   (h,128,512)
  const size_t O_KEXT = O_WO + (size_t)DIM * DIM * 2;          // wo_b  (2048,2048)
  const size_t O_QABS = O_KEXT + (size_t)MM * 576 * 2;         // Kext  (4096,576)
  const size_t O_QPE  = O_QABS + (size_t)HH * MM * CKV * 2;    // qabs  (h,4096,512)
  const size_t O_O2   = O_QPE + (size_t)HH * MM * DR * 2;      // qpe   (h,4096,64)
  const size_t O_T    = O_O2 + (size_t)MM * DIM * 2;           // o2    (4096,2048)
  const size_t O_XB   = O_T;                                   // xb    (4096,2048)  [transient]
  const size_t O_QN   = O_T;                                   // qnope (h,4096,128) [reuses xb]
  const size_t O_OATT = O_T;                                   // O     (h,4096,512) [reuses xb+Y]
  const size_t O_Y    = O_T + (size_t)MM * DIM * 2;            // Y     (4096,3712)

  ushort_t* wcat  = (ushort_t*)(ws + O_WCAT);
  ushort_t* wbT   = (ushort_t*)(ws + O_WBT);
  ushort_t* wbv   = (ushort_t*)(ws + O_WBV);
  ushort_t* wo_b  = (ushort_t*)(ws + O_WO);
  ushort_t* kext  = (ushort_t*)(ws + O_KEXT);
  ushort_t* qabs  = (ushort_t*)(ws + O_QABS);
  ushort_t* qpe   = (ushort_t*)(ws + O_QPE);
  ushort_t* o2    = (ushort_t*)(ws + O_O2);
  ushort_t* xb    = (ushort_t*)(ws + O_XB);
  ushort_t* qnope = (ushort_t*)(ws + O_QN);
  ushort_t* oatt  = (ushort_t*)(ws + O_OATT);
  ushort_t* Y     = (ushort_t*)(ws + O_Y);

  double msc = 0.1 * log(40.0) + 1.0;
  float scale = (float)(pow((double)QKH, -0.5) * msc * msc);

  dim3 blk(256);
  // conversions
  f32_to_bf16_k<<<dim3(4096), blk, 0, stream>>>(x, xb, (long)MM * DIM);
  build_wcat_k<<<dim3(4096), blk, 0, stream>>>(wq, wkva, wcat);
  build_wb_k<<<dim3(1024), blk, 0, stream>>>(wkvb, wbT, wbv);
  f32_to_bf16_k<<<dim3(2048), blk, 0, stream>>>(wo, wo_b, (long)DIM * DIM);

  // G1: Y = x @ [wq; wkv_a]^T   (4096, 3712, K=2048)
  gemm_bt<ushort_t><<<dim3(32, 29, 1), blk, 0, stream>>>(
      xb, wcat, Y, DIM, DIM, DIM, NPAD, 0, 0, 0);

  // postproc
  postproc_k<<<dim3(MM), blk, 0, stream>>>(Y, fcos, fsin, kvw, qnope, qpe, kext);

  // G2: qabs[h] = qnope[h] @ wbT[h]^T   (4096, 512, K=128) per head
  gemm_bt<ushort_t><<<dim3(32, 4, HH), blk, 0, stream>>>(
      qnope, wbT, qabs, DN, DN, DN, CKV,
      (long)MM * DN, (long)CKV * DN, (long)MM * CKV);

  // attention
  attn_k<<<dim3(SS / 64, BB * HH), blk, 0, stream>>>(qabs, qpe, kext, oatt, scale);

  // G4: o2[:, h*128:(h+1)*128] = O[h] @ wbv[h]^T   (4096, 128, K=512) per head
  gemm_bt<ushort_t><<<dim3(32, 1, HH), blk, 0, stream>>>(
      oatt, wbv, o2, CKV, CKV, CKV, DIM,
      (long)MM * CKV, (long)DN * CKV, (long)DN);

  // G5: out = o2 @ wo^T   (4096, 2048, K=2048)
  gemm_bt<float><<<dim3(32, 16, 1), blk, 0, stream>>>(
      o2, wo_b, out, DIM, DIM, DIM, DIM, 0, 0, 0);
}